// Round 10
// baseline (824.198 us; speedup 1.0000x reference)
//
#include <hip/hip_runtime.h>
#include <hip/hip_bf16.h>

typedef unsigned short u16;
typedef __attribute__((ext_vector_type(8))) short short8;
typedef __attribute__((ext_vector_type(4))) float f32x4;

#define HC 256      // H*C (all three layers output 256)
#define NHEAD 4

// ---------------------------------------------------------------------------
// bf16 helpers: truncation split (hi = top 16 bits, lo = rne(v - hi))
// ---------------------------------------------------------------------------
__device__ __forceinline__ u16 f2b_rne(float v) {
  __hip_bfloat16 b = __float2bfloat16(v);
  union { __hip_bfloat16 b; u16 u; } cv; cv.b = b; return cv.u;
}

// ---------------------------------------------------------------------------
// W convert (all 3 layers, one dispatch):
// Wth/Wtl[n*K + k] = split_bf16(W[k*256 + n])  (transposed, k-major)
// ---------------------------------------------------------------------------
__device__ __forceinline__ void w_split_store(const float* W, u16* Th, u16* Tl,
                                              int K, int off) {
  int k = off >> 8, n = off & 255;
  float v = W[off];
  unsigned bits = __float_as_uint(v);
  u16 hi = (u16)(bits >> 16);
  float hf = __uint_as_float((unsigned)hi << 16);
  u16 lo = f2b_rne(v - hf);
  Th[n * K + k] = hi;
  Tl[n * K + k] = lo;
}

__global__ void convert_w3(const float* __restrict__ W1, const float* __restrict__ W2,
                           const float* __restrict__ W3,
                           u16* __restrict__ Th1, u16* __restrict__ Tl1,
                           u16* __restrict__ Th2, u16* __restrict__ Tl2,
                           u16* __restrict__ Th3, u16* __restrict__ Tl3) {
  int id = blockIdx.x * 256 + threadIdx.x;
  const int S1 = 128 * 256, S2 = 256 * 256;
  if (id < S1) w_split_store(W1, Th1, Tl1, 128, id);
  else if (id < S1 + S2) w_split_store(W2, Th2, Tl2, 256, id - S1);
  else if (id < S1 + 2 * S2) w_split_store(W3, Th3, Tl3, 256, id - S1 - S2);
}

__device__ __forceinline__ float lky(float e) {
  return (e >= 0.f) ? e : 0.2f * e;
}

__device__ __forceinline__ float comp4(float4 v, int i) {
  return (i == 0) ? v.x : (i == 1) ? v.y : (i == 2) ? v.z : v.w;
}

// ---------------------------------------------------------------------------
// GEMM: C[M,256] = A[M,K] @ B[K,256] via split-bf16 MFMA 16x16x32.
// Block 128x128x64, 4 waves 2x2, wave tile 64x64 (4x4 frags).
// Co-XCD pairing swizzle (A-panel L2 sharing). Fused alpha epilogue.
// ---------------------------------------------------------------------------
#define GBM 128
#define GBN 128
#define GBK 64

__global__ __launch_bounds__(256, 2) void gemm_mfma(
    const float* __restrict__ A, const u16* __restrict__ Bth,
    const u16* __restrict__ Btl, float* __restrict__ C,
    const float* __restrict__ a_src, const float* __restrict__ a_dst,
    float* __restrict__ AS, float* __restrict__ AD, int M, int K, int nMb) {
  __shared__ u16 AH[128 * 64], AL[128 * 64], BH[128 * 64], BL[128 * 64];
  const int tid = threadIdx.x;
  const int lane = tid & 63;
  const int wave = tid >> 6;
  const int wm = (wave & 1) * 64;
  const int wn = (wave >> 1) * 64;

  const int bid = blockIdx.x;
  const int g = bid >> 4;
  const int r = bid & 15;
  const int base = g * 8;
  const int rem = nMb - base;
  int bmi, bni;
  if (rem >= 8) { bmi = base + (r & 7); bni = r >> 3; }
  else          { bmi = base + (r % rem); bni = r / rem; }
  const int bm = bmi * GBM;
  const int bn = bni * GBN;

  const int srow = tid >> 1;
  const int skh  = (tid & 1) * 32;

  f32x4 acc[4][4] = {};
  const int agm = (bm + srow < M) ? (bm + srow) : (M - 1);

  for (int bk = 0; bk < K; bk += GBK) {
    float4 a0[4], a1[4];
    const float* arow = A + (size_t)agm * K + bk + skh;
#pragma unroll
    for (int u = 0; u < 4; ++u) {
      a0[u] = ((const float4*)arow)[2 * u];
      a1[u] = ((const float4*)arow)[2 * u + 1];
    }
    short8 sbh[4], sbl[4];
    const u16* bhrow = Bth + (size_t)(bn + srow) * K + bk + skh;
    const u16* blrow = Btl + (size_t)(bn + srow) * K + bk + skh;
#pragma unroll
    for (int u = 0; u < 4; ++u) {
      sbh[u] = *(const short8*)(bhrow + 8 * u);
      sbl[u] = *(const short8*)(blrow + 8 * u);
    }
    __syncthreads();
#pragma unroll
    for (int u = 0; u < 4; ++u) {
      int idx = (srow * 64 + skh + u * 8) ^ ((srow & 7) << 3);
      float va[8] = {a0[u].x, a0[u].y, a0[u].z, a0[u].w,
                     a1[u].x, a1[u].y, a1[u].z, a1[u].w};
      short8 hi, lo;
#pragma unroll
      for (int j = 0; j < 8; ++j) {
        unsigned bits = __float_as_uint(va[j]);
        u16 h = (u16)(bits >> 16);
        float hf = __uint_as_float((unsigned)h << 16);
        u16 l = f2b_rne(va[j] - hf);
        ((short*)&hi)[j] = (short)h;
        ((short*)&lo)[j] = (short)l;
      }
      *(short8*)&AH[idx] = hi;
      *(short8*)&AL[idx] = lo;
      *(short8*)&BH[idx] = sbh[u];
      *(short8*)&BL[idx] = sbl[u];
    }
    __syncthreads();
#pragma unroll
    for (int ks = 0; ks < 2; ++ks) {
      const int k0 = ks * 32 + (lane >> 4) * 8;
      short8 fah[4], fal[4], fbh[4], fbl[4];
#pragma unroll
      for (int mt = 0; mt < 4; ++mt) {
        int rr = wm + mt * 16 + (lane & 15);
        int idx = (rr * 64 + k0) ^ ((rr & 7) << 3);
        fah[mt] = *(const short8*)&AH[idx];
        fal[mt] = *(const short8*)&AL[idx];
      }
#pragma unroll
      for (int nt = 0; nt < 4; ++nt) {
        int rr = wn + nt * 16 + (lane & 15);
        int idx = (rr * 64 + k0) ^ ((rr & 7) << 3);
        fbh[nt] = *(const short8*)&BH[idx];
        fbl[nt] = *(const short8*)&BL[idx];
      }
#pragma unroll
      for (int mt = 0; mt < 4; ++mt)
#pragma unroll
        for (int nt = 0; nt < 4; ++nt) {
          acc[mt][nt] = __builtin_amdgcn_mfma_f32_16x16x32_bf16(
              fbh[nt], fah[mt], acc[mt][nt], 0, 0, 0);
          acc[mt][nt] = __builtin_amdgcn_mfma_f32_16x16x32_bf16(
              fbh[nt], fal[mt], acc[mt][nt], 0, 0, 0);
          acc[mt][nt] = __builtin_amdgcn_mfma_f32_16x16x32_bf16(
              fbl[nt], fah[mt], acc[mt][nt], 0, 0, 0);
        }
    }
  }
  // ---- fused alpha epilogue + C store
  const int headq = (bn + wn) >> 6;
  float4 sa[4], da[4];
#pragma unroll
  for (int nt = 0; nt < 4; ++nt) {
    sa[nt] = ((const float4*)a_src)[headq * 16 + nt * 4 + (lane >> 4)];
    da[nt] = ((const float4*)a_dst)[headq * 16 + nt * 4 + (lane >> 4)];
  }
#pragma unroll
  for (int mt = 0; mt < 4; ++mt) {
    const int row = bm + wm + mt * 16 + (lane & 15);
    float ps = 0.f, pd = 0.f;
#pragma unroll
    for (int nt = 0; nt < 4; ++nt) {
      ps += acc[mt][nt][0] * sa[nt].x + acc[mt][nt][1] * sa[nt].y +
            acc[mt][nt][2] * sa[nt].z + acc[mt][nt][3] * sa[nt].w;
      pd += acc[mt][nt][0] * da[nt].x + acc[mt][nt][1] * da[nt].y +
            acc[mt][nt][2] * da[nt].z + acc[mt][nt][3] * da[nt].w;
    }
    ps += __shfl_xor(ps, 16); ps += __shfl_xor(ps, 32);
    pd += __shfl_xor(pd, 16); pd += __shfl_xor(pd, 32);
    if (row < M) {
      float* cp = C + (size_t)row * HC + bn + wn + (lane >> 4) * 4;
#pragma unroll
      for (int nt = 0; nt < 4; ++nt)
        *(f32x4*)(cp + nt * 16) = acc[mt][nt];
      if ((lane >> 4) == 0) {
        AS[row * NHEAD + headq] = ps;
        AD[row * NHEAD + headq] = pd;
      }
    }
  }
}

// ---------------------------------------------------------------------------
// softmax_stats: per node, per head: mm = max_e lky(as_e + ad) and
// inv_l = 1/(sum_e exp(lky(as_e+ad) - mm) + 1e-16). 1 wave per node.
// All gathers hit the L2-resident as-table (800 KB).
// ---------------------------------------------------------------------------
__global__ __launch_bounds__(256) void softmax_stats(
    const float* __restrict__ as_g, const float* __restrict__ ad_g,
    const int* __restrict__ row_ptr, const int* __restrict__ csr_src,
    float* __restrict__ MM, float* __restrict__ INVL, int N) {
  const int wave = threadIdx.x >> 6;
  const int lane = threadIdx.x & 63;
  const int n = blockIdx.x * 4 + wave;
  if (n >= N) return;
  const float4* __restrict__ as4 = (const float4*)as_g;
  const int beg = row_ptr[n];
  const int end = row_ptr[n + 1];

  // pass A: per-head max of as
  float4 m4 = make_float4(-1e30f, -1e30f, -1e30f, -1e30f);
  for (int j = beg + lane; j < end; j += 64) {
    float4 a = as4[csr_src[j]];
    m4.x = fmaxf(m4.x, a.x); m4.y = fmaxf(m4.y, a.y);
    m4.z = fmaxf(m4.z, a.z); m4.w = fmaxf(m4.w, a.w);
  }
#pragma unroll
  for (int off = 32; off > 0; off >>= 1) {
    m4.x = fmaxf(m4.x, __shfl_xor(m4.x, off));
    m4.y = fmaxf(m4.y, __shfl_xor(m4.y, off));
    m4.z = fmaxf(m4.z, __shfl_xor(m4.z, off));
    m4.w = fmaxf(m4.w, __shfl_xor(m4.w, off));
  }
  const float4 ad4 = ((const float4*)ad_g)[n];
  float4 mm4;
  mm4.x = lky(ad4.x + m4.x);
  mm4.y = lky(ad4.y + m4.y);
  mm4.z = lky(ad4.z + m4.z);
  mm4.w = lky(ad4.w + m4.w);

  // pass B: denominators
  float4 l4 = make_float4(0.f, 0.f, 0.f, 0.f);
  for (int j = beg + lane; j < end; j += 64) {
    float4 a = as4[csr_src[j]];
    l4.x += __expf(lky(a.x + ad4.x) - mm4.x);
    l4.y += __expf(lky(a.y + ad4.y) - mm4.y);
    l4.z += __expf(lky(a.z + ad4.z) - mm4.z);
    l4.w += __expf(lky(a.w + ad4.w) - mm4.w);
  }
#pragma unroll
  for (int off = 32; off > 0; off >>= 1) {
    l4.x += __shfl_xor(l4.x, off);
    l4.y += __shfl_xor(l4.y, off);
    l4.z += __shfl_xor(l4.z, off);
    l4.w += __shfl_xor(l4.w, off);
  }
  if (lane == 0) {
    ((float4*)MM)[n] = mm4;
    float4 inv;
    inv.x = 1.f / (l4.x + 1e-16f);
    inv.y = 1.f / (l4.y + 1e-16f);
    inv.z = 1.f / (l4.z + 1e-16f);
    inv.w = 1.f / (l4.w + 1e-16f);
    ((float4*)INVL)[n] = inv;
  }
}

// ---------------------------------------------------------------------------
// aggregate_sliced: XCD-column-sliced weighted gather.
// Block b handles slice q = b&7 (channels q*32..q*32+31, 128B contiguous,
// single head q>>1) of 4 nodes (b>>3). Round-robin dispatch puts slice q on
// XCD q -> each XCD's h working set is 51.2/8 = 6.4 MB (~L2-sized) instead
// of the whole table. Wave = 1 node; lanes = 2 edges x 32 channels; 16
// edges in flight. Stats (mm, inv_l) precomputed by softmax_stats.
// ---------------------------------------------------------------------------
__global__ __launch_bounds__(256) void aggregate_sliced(
    const float* __restrict__ h, const float* __restrict__ as_g,
    const float* __restrict__ ad_g, const float* __restrict__ MM,
    const float* __restrict__ INVL, const int* __restrict__ row_ptr,
    const int* __restrict__ csr_src, const float* __restrict__ bias,
    float* __restrict__ out, int relu_flag, int N) {
  const int q = blockIdx.x & 7;
  const int ng = blockIdx.x >> 3;
  const int wave = threadIdx.x >> 6;
  const int lane = threadIdx.x & 63;
  const int n = ng * 4 + wave;
  if (n >= N) return;
  const int head = q >> 1;
  const int epar = lane >> 5;            // which of 2 concurrent edges
  const int c = lane & 31;               // channel within slice

  const int beg = row_ptr[n];
  const int end = row_ptr[n + 1];
  const float ad = ad_g[n * NHEAD + head];
  const float mm = MM[n * NHEAD + head];
  const float il = INVL[n * NHEAD + head];
  const float* __restrict__ hsl = h + q * 32 + c;

  float acc = 0.f;
  for (int j0 = beg; j0 < end; j0 += 16) {
    int s[8];
    float ae[8];
    float hv[8];
#pragma unroll
    for (int u = 0; u < 8; ++u) {
      int j = j0 + 2 * u + epar;
      s[u] = csr_src[(j < end) ? j : (end - 1)];
    }
#pragma unroll
    for (int u = 0; u < 8; ++u) ae[u] = as_g[s[u] * NHEAD + head];
#pragma unroll
    for (int u = 0; u < 8; ++u) hv[u] = hsl[(size_t)s[u] * HC];
#pragma unroll
    for (int u = 0; u < 8; ++u) {
      float p = __expf(lky(ae[u] + ad) - mm);
      p = (j0 + 2 * u + epar < end) ? p : 0.f;
      acc = fmaf(p, hv[u], acc);
    }
  }
  acc += __shfl_xor(acc, 32);            // combine the 2 edge-parity halves
  if (epar == 0) {
    float o = acc * il + bias[q * 32 + c];
    if (relu_flag) o = fmaxf(o, 0.f);
    out[(size_t)n * HC + q * 32 + c] = o;
  }
}

// ---------------------------------------------------------------------------
// edge_index dtype sniffer: flag=1 if int64 layout, 0 if int32.
// ---------------------------------------------------------------------------
__global__ void detect_kernel(const int* __restrict__ ei32, int* flag) {
  const int t = threadIdx.x;   // 64 threads
  int bad = 0;
#pragma unroll
  for (int r = 0; r < 4; ++r) {
    int i = r * 64 + t;
    if (ei32[2 * i + 1] != 0) bad = 1;
  }
#pragma unroll
  for (int off = 32; off > 0; off >>= 1) bad |= __shfl_down(bad, off);
  if (t == 0) *flag = bad ? 0 : 1;
}

__device__ inline void edge_pair(const int* __restrict__ ei32,
                                 const long long* __restrict__ ei64, int is64,
                                 int e, int E, int& src, int& dst) {
  if (e < E) {
    if (is64) { src = (int)ei64[e]; dst = (int)ei64[(size_t)E + e]; }
    else      { src = ei32[e];      dst = ei32[(size_t)E + e]; }
  } else {
    src = dst = e - E;   // self loops appended
  }
}

__global__ void count_kernel(const int* __restrict__ ei32, const int* __restrict__ flag,
                             int* __restrict__ cnt, int E, int Nn) {
  int e = blockIdx.x * blockDim.x + threadIdx.x;
  if (e >= E + Nn) return;
  int is64 = *flag;
  int src, dst;
  edge_pair(ei32, (const long long*)ei32, is64, e, E, src, dst);
  atomicAdd(&cnt[dst], 1);
}

__global__ void scatter_kernel(const int* __restrict__ ei32, const int* __restrict__ flag,
                               int* __restrict__ cursor, int* __restrict__ csr_src,
                               int E, int Nn) {
  int e = blockIdx.x * blockDim.x + threadIdx.x;
  if (e >= E + Nn) return;
  int is64 = *flag;
  int src, dst;
  edge_pair(ei32, (const long long*)ei32, is64, e, E, src, dst);
  int pos = atomicAdd(&cursor[dst], 1);
  csr_src[pos] = src;
}

// ---------------------------------------------------------------------------
// hierarchical exclusive scan
// ---------------------------------------------------------------------------
__global__ __launch_bounds__(256) void scan_blocks(
    const int* __restrict__ cnt, int* __restrict__ local,
    int* __restrict__ partials, int Nn) {
  __shared__ int swave[4];
  const int t = threadIdx.x, lane = t & 63, w = t >> 6;
  const int idx = blockIdx.x * 256 + t;
  int v = (idx < Nn) ? cnt[idx] : 0;
  int x = v;
#pragma unroll
  for (int off = 1; off < 64; off <<= 1) {
    int y = __shfl_up(x, off);
    if (lane >= off) x += y;
  }
  if (lane == 63) swave[w] = x;
  __syncthreads();
  int wofs = 0;
#pragma unroll
  for (int i = 0; i < 3; ++i) wofs += (i < w) ? swave[i] : 0;
  if (idx < Nn) local[idx] = wofs + x - v;
  if (t == 255) partials[blockIdx.x] = wofs + x;
}

__global__ __launch_bounds__(256) void scan_partials(
    int* __restrict__ partials, int nb, int* __restrict__ total_out) {
  __shared__ int swave[4];
  const int t = threadIdx.x, lane = t & 63, w = t >> 6;
  int v = (t < nb) ? partials[t] : 0;
  int x = v;
#pragma unroll
  for (int off = 1; off < 64; off <<= 1) {
    int y = __shfl_up(x, off);
    if (lane >= off) x += y;
  }
  if (lane == 63) swave[w] = x;
  __syncthreads();
  int wofs = 0;
#pragma unroll
  for (int i = 0; i < 3; ++i) wofs += (i < w) ? swave[i] : 0;
  int excl = wofs + x - v;
  if (t < nb) partials[t] = excl;
  if (t == nb - 1) *total_out = excl + v;
}

__global__ void add_offsets(const int* __restrict__ local,
                            const int* __restrict__ partials,
                            int* __restrict__ row_ptr, int* __restrict__ cursor,
                            int Nn) {
  const int idx = blockIdx.x * 256 + threadIdx.x;
  if (idx < Nn) {
    int v = local[idx] + partials[blockIdx.x];
    row_ptr[idx] = v;
    cursor[idx] = v;
  }
}

// ---------------------------------------------------------------------------
static inline size_t align_up(size_t v) { return (v + 255) & ~(size_t)255; }

extern "C" void kernel_launch(void* const* d_in, const int* in_sizes, int n_in,
                              void* d_out, int out_size, void* d_ws, size_t ws_size,
                              hipStream_t stream) {
  const float* x      = (const float*)d_in[0];
  const int*   ei32   = (const int*)d_in[1];
  const float* W1     = (const float*)d_in[2];
  const float* asrc1  = (const float*)d_in[3];
  const float* adst1  = (const float*)d_in[4];
  const float* b1     = (const float*)d_in[5];
  const float* W2     = (const float*)d_in[6];
  const float* asrc2  = (const float*)d_in[7];
  const float* adst2  = (const float*)d_in[8];
  const float* b2     = (const float*)d_in[9];
  const float* W3     = (const float*)d_in[10];
  const float* asrc3  = (const float*)d_in[11];
  const float* adst3  = (const float*)d_in[12];
  const float* b3     = (const float*)d_in[13];

  const int N = in_sizes[0] / 128;   // 50000
  const int E = in_sizes[1] / 2;     // 800000
  const int ET = E + N;              // with self loops
  float* out = (float*)d_out;
  const int nb = (N + 255) / 256;

  // ---- workspace carve
  char* w = (char*)d_ws;
  float* H       = (float*)w; w += align_up((size_t)N * HC * sizeof(float));
  float* AS      = (float*)w; w += align_up((size_t)N * NHEAD * sizeof(float));
  float* AD      = (float*)w; w += align_up((size_t)N * NHEAD * sizeof(float));
  float* MM      = (float*)w; w += align_up((size_t)N * NHEAD * sizeof(float));
  float* INVL    = (float*)w; w += align_up((size_t)N * NHEAD * sizeof(float));
  int*   cnt     = (int*)w;   w += align_up((size_t)N * sizeof(int));
  int*   local   = (int*)w;   w += align_up((size_t)N * sizeof(int));
  int*   row_ptr = (int*)w;   w += align_up((size_t)(N + 1) * sizeof(int));
  int*   cursor  = (int*)w;   w += align_up((size_t)(N + 1) * sizeof(int));
  int*   parts   = (int*)w;   w += align_up(256 * sizeof(int));
  int*   csr_src = (int*)w;   w += align_up((size_t)ET * sizeof(int));
  u16*   Wth1    = (u16*)w;   w += align_up((size_t)128 * 256 * sizeof(u16));
  u16*   Wtl1    = (u16*)w;   w += align_up((size_t)128 * 256 * sizeof(u16));
  u16*   Wth2    = (u16*)w;   w += align_up((size_t)256 * 256 * sizeof(u16));
  u16*   Wtl2    = (u16*)w;   w += align_up((size_t)256 * 256 * sizeof(u16));
  u16*   Wth3    = (u16*)w;   w += align_up((size_t)256 * 256 * sizeof(u16));
  u16*   Wtl3    = (u16*)w;   w += align_up((size_t)256 * 256 * sizeof(u16));
  int*   flag    = (int*)w;   w += align_up(sizeof(int));

  // ---- weight conversion + CSR build
  convert_w3<<<(128 * 256 + 2 * 256 * 256 + 255) / 256, 256, 0, stream>>>(
      W1, W2, W3, Wth1, Wtl1, Wth2, Wtl2, Wth3, Wtl3);
  hipMemsetAsync(cnt, 0, (size_t)N * sizeof(int), stream);
  detect_kernel<<<1, 64, 0, stream>>>(ei32, flag);
  count_kernel<<<(ET + 255) / 256, 256, 0, stream>>>(ei32, flag, cnt, E, N);
  scan_blocks<<<nb, 256, 0, stream>>>(cnt, local, parts, N);
  scan_partials<<<1, 256, 0, stream>>>(parts, nb, row_ptr + N);
  add_offsets<<<nb, 256, 0, stream>>>(local, parts, row_ptr, cursor, N);
  scatter_kernel<<<(ET + 255) / 256, 256, 0, stream>>>(ei32, flag, cursor, csr_src, E, N);

  const int nMb = (N + GBM - 1) / GBM;           // 391
  const int gemm_blocks = nMb * 2;               // 1D swizzled grid
  const int ablk = (N + 3) / 4;
  const int sblk = ablk * 8;                     // sliced aggregate grid

  // ---- layer 1 (K=128), ReLU
  gemm_mfma<<<gemm_blocks, 256, 0, stream>>>(x, Wth1, Wtl1, H,
      asrc1, adst1, AS, AD, N, 128, nMb);
  softmax_stats<<<ablk, 256, 0, stream>>>(AS, AD, row_ptr, csr_src, MM, INVL, N);
  aggregate_sliced<<<sblk, 256, 0, stream>>>(H, AS, AD, MM, INVL, row_ptr,
      csr_src, b1, out, 1, N);

  // ---- layer 2 (K=256), ReLU
  gemm_mfma<<<gemm_blocks, 256, 0, stream>>>(out, Wth2, Wtl2, H,
      asrc2, adst2, AS, AD, N, 256, nMb);
  softmax_stats<<<ablk, 256, 0, stream>>>(AS, AD, row_ptr, csr_src, MM, INVL, N);
  aggregate_sliced<<<sblk, 256, 0, stream>>>(H, AS, AD, MM, INVL, row_ptr,
      csr_src, b2, out, 1, N);

  // ---- layer 3 (K=256), no ReLU
  gemm_mfma<<<gemm_blocks, 256, 0, stream>>>(out, Wth3, Wtl3, H,
      asrc3, adst3, AS, AD, N, 256, nMb);
  softmax_stats<<<ablk, 256, 0, stream>>>(AS, AD, row_ptr, csr_src, MM, INVL, N);
  aggregate_sliced<<<sblk, 256, 0, stream>>>(H, AS, AD, MM, INVL, row_ptr,
      csr_src, b3, out, 0, N);
}

// Round 11
// 759.535 us; speedup vs baseline: 1.0851x; 1.0851x over previous
//
#include <hip/hip_runtime.h>
#include <hip/hip_bf16.h>

typedef unsigned short u16;
typedef __attribute__((ext_vector_type(8))) short short8;
typedef __attribute__((ext_vector_type(4))) float f32x4;

#define HC 256      // H*C (all three layers output 256)
#define NHEAD 4

// ---------------------------------------------------------------------------
// bf16 helpers: truncation split (hi = top 16 bits, lo = rne(v - hi))
// ---------------------------------------------------------------------------
__device__ __forceinline__ u16 f2b_rne(float v) {
  __hip_bfloat16 b = __float2bfloat16(v);
  union { __hip_bfloat16 b; u16 u; } cv; cv.b = b; return cv.u;
}

// ---------------------------------------------------------------------------
// W convert (all 3 layers, one dispatch):
// Wth/Wtl[n*K + k] = split_bf16(W[k*256 + n])  (transposed, k-major)
// ---------------------------------------------------------------------------
__device__ __forceinline__ void w_split_store(const float* W, u16* Th, u16* Tl,
                                              int K, int off) {
  int k = off >> 8, n = off & 255;
  float v = W[off];
  unsigned bits = __float_as_uint(v);
  u16 hi = (u16)(bits >> 16);
  float hf = __uint_as_float((unsigned)hi << 16);
  u16 lo = f2b_rne(v - hf);
  Th[n * K + k] = hi;
  Tl[n * K + k] = lo;
}

__global__ void convert_w3(const float* __restrict__ W1, const float* __restrict__ W2,
                           const float* __restrict__ W3,
                           u16* __restrict__ Th1, u16* __restrict__ Tl1,
                           u16* __restrict__ Th2, u16* __restrict__ Tl2,
                           u16* __restrict__ Th3, u16* __restrict__ Tl3) {
  int id = blockIdx.x * 256 + threadIdx.x;
  const int S1 = 128 * 256, S2 = 256 * 256;
  if (id < S1) w_split_store(W1, Th1, Tl1, 128, id);
  else if (id < S1 + S2) w_split_store(W2, Th2, Tl2, 256, id - S1);
  else if (id < S1 + 2 * S2) w_split_store(W3, Th3, Tl3, 256, id - S1 - S2);
}

__device__ __forceinline__ float lky(float e) {
  return (e >= 0.f) ? e : 0.2f * e;
}

__device__ __forceinline__ float comp4(float4 v, int i) {
  return (i == 0) ? v.x : (i == 1) ? v.y : (i == 2) ? v.z : v.w;
}

// ---------------------------------------------------------------------------
// GEMM: C[M,256] = A[M,K] @ B[K,256] via split-bf16 MFMA 16x16x32.
// Block 128x128x64, 4 waves 2x2, wave tile 64x64 (4x4 frags).
// Co-XCD pairing swizzle (A-panel L2 sharing). Fused alpha epilogue.
// ---------------------------------------------------------------------------
#define GBM 128
#define GBN 128
#define GBK 64

__global__ __launch_bounds__(256, 2) void gemm_mfma(
    const float* __restrict__ A, const u16* __restrict__ Bth,
    const u16* __restrict__ Btl, float* __restrict__ C,
    const float* __restrict__ a_src, const float* __restrict__ a_dst,
    float* __restrict__ AS, float* __restrict__ AD, int M, int K, int nMb) {
  __shared__ u16 AH[128 * 64], AL[128 * 64], BH[128 * 64], BL[128 * 64];
  const int tid = threadIdx.x;
  const int lane = tid & 63;
  const int wave = tid >> 6;
  const int wm = (wave & 1) * 64;
  const int wn = (wave >> 1) * 64;

  const int bid = blockIdx.x;
  const int g = bid >> 4;
  const int r = bid & 15;
  const int base = g * 8;
  const int rem = nMb - base;
  int bmi, bni;
  if (rem >= 8) { bmi = base + (r & 7); bni = r >> 3; }
  else          { bmi = base + (r % rem); bni = r / rem; }
  const int bm = bmi * GBM;
  const int bn = bni * GBN;

  const int srow = tid >> 1;
  const int skh  = (tid & 1) * 32;

  f32x4 acc[4][4] = {};
  const int agm = (bm + srow < M) ? (bm + srow) : (M - 1);

  for (int bk = 0; bk < K; bk += GBK) {
    float4 a0[4], a1[4];
    const float* arow = A + (size_t)agm * K + bk + skh;
#pragma unroll
    for (int u = 0; u < 4; ++u) {
      a0[u] = ((const float4*)arow)[2 * u];
      a1[u] = ((const float4*)arow)[2 * u + 1];
    }
    short8 sbh[4], sbl[4];
    const u16* bhrow = Bth + (size_t)(bn + srow) * K + bk + skh;
    const u16* blrow = Btl + (size_t)(bn + srow) * K + bk + skh;
#pragma unroll
    for (int u = 0; u < 4; ++u) {
      sbh[u] = *(const short8*)(bhrow + 8 * u);
      sbl[u] = *(const short8*)(blrow + 8 * u);
    }
    __syncthreads();
#pragma unroll
    for (int u = 0; u < 4; ++u) {
      int idx = (srow * 64 + skh + u * 8) ^ ((srow & 7) << 3);
      float va[8] = {a0[u].x, a0[u].y, a0[u].z, a0[u].w,
                     a1[u].x, a1[u].y, a1[u].z, a1[u].w};
      short8 hi, lo;
#pragma unroll
      for (int j = 0; j < 8; ++j) {
        unsigned bits = __float_as_uint(va[j]);
        u16 h = (u16)(bits >> 16);
        float hf = __uint_as_float((unsigned)h << 16);
        u16 l = f2b_rne(va[j] - hf);
        ((short*)&hi)[j] = (short)h;
        ((short*)&lo)[j] = (short)l;
      }
      *(short8*)&AH[idx] = hi;
      *(short8*)&AL[idx] = lo;
      *(short8*)&BH[idx] = sbh[u];
      *(short8*)&BL[idx] = sbl[u];
    }
    __syncthreads();
#pragma unroll
    for (int ks = 0; ks < 2; ++ks) {
      const int k0 = ks * 32 + (lane >> 4) * 8;
      short8 fah[4], fal[4], fbh[4], fbl[4];
#pragma unroll
      for (int mt = 0; mt < 4; ++mt) {
        int rr = wm + mt * 16 + (lane & 15);
        int idx = (rr * 64 + k0) ^ ((rr & 7) << 3);
        fah[mt] = *(const short8*)&AH[idx];
        fal[mt] = *(const short8*)&AL[idx];
      }
#pragma unroll
      for (int nt = 0; nt < 4; ++nt) {
        int rr = wn + nt * 16 + (lane & 15);
        int idx = (rr * 64 + k0) ^ ((rr & 7) << 3);
        fbh[nt] = *(const short8*)&BH[idx];
        fbl[nt] = *(const short8*)&BL[idx];
      }
#pragma unroll
      for (int mt = 0; mt < 4; ++mt)
#pragma unroll
        for (int nt = 0; nt < 4; ++nt) {
          acc[mt][nt] = __builtin_amdgcn_mfma_f32_16x16x32_bf16(
              fbh[nt], fah[mt], acc[mt][nt], 0, 0, 0);
          acc[mt][nt] = __builtin_amdgcn_mfma_f32_16x16x32_bf16(
              fbh[nt], fal[mt], acc[mt][nt], 0, 0, 0);
          acc[mt][nt] = __builtin_amdgcn_mfma_f32_16x16x32_bf16(
              fbl[nt], fah[mt], acc[mt][nt], 0, 0, 0);
        }
    }
  }
  // ---- fused alpha epilogue + C store
  const int headq = (bn + wn) >> 6;
  float4 sa[4], da[4];
#pragma unroll
  for (int nt = 0; nt < 4; ++nt) {
    sa[nt] = ((const float4*)a_src)[headq * 16 + nt * 4 + (lane >> 4)];
    da[nt] = ((const float4*)a_dst)[headq * 16 + nt * 4 + (lane >> 4)];
  }
#pragma unroll
  for (int mt = 0; mt < 4; ++mt) {
    const int row = bm + wm + mt * 16 + (lane & 15);
    float ps = 0.f, pd = 0.f;
#pragma unroll
    for (int nt = 0; nt < 4; ++nt) {
      ps += acc[mt][nt][0] * sa[nt].x + acc[mt][nt][1] * sa[nt].y +
            acc[mt][nt][2] * sa[nt].z + acc[mt][nt][3] * sa[nt].w;
      pd += acc[mt][nt][0] * da[nt].x + acc[mt][nt][1] * da[nt].y +
            acc[mt][nt][2] * da[nt].z + acc[mt][nt][3] * da[nt].w;
    }
    ps += __shfl_xor(ps, 16); ps += __shfl_xor(ps, 32);
    pd += __shfl_xor(pd, 16); pd += __shfl_xor(pd, 32);
    if (row < M) {
      float* cp = C + (size_t)row * HC + bn + wn + (lane >> 4) * 4;
#pragma unroll
      for (int nt = 0; nt < 4; ++nt)
        *(f32x4*)(cp + nt * 16) = acc[mt][nt];
      if ((lane >> 4) == 0) {
        AS[row * NHEAD + headq] = ps;
        AD[row * NHEAD + headq] = pd;
      }
    }
  }
}

// ---------------------------------------------------------------------------
// edge_weights: 1 wave per node, lane = head(2b) x sub(4b).
// Per-head segment max (exact, leaky monotone), per-edge UNNORMALIZED
// w = exp(lky(as+ad) - mm) into w_buf[j*4+head], inv_l[n*4+h] = 1/sum.
// All gathers hit the L2-resident as-table (800 KB). ~18 us (R5 measured).
// Removes ALL exp/as-gather VALU from the sliced h-gather (R10's 102%
// VALUBusy lesson: slicing x8-replicates any per-edge VALU left in it).
// ---------------------------------------------------------------------------
__global__ __launch_bounds__(256) void edge_weights(
    const float* __restrict__ as_g, const float* __restrict__ ad_g,
    const int* __restrict__ row_ptr, const int* __restrict__ csr_src,
    float* __restrict__ w_buf, float* __restrict__ inv_l, int N) {
  const int wave = threadIdx.x >> 6;
  const int lane = threadIdx.x & 63;
  const int n = blockIdx.x * 4 + wave;
  if (n >= N) return;
  const int head = lane >> 4;
  const int sub = lane & 15;
  const float4* __restrict__ as4 = (const float4*)as_g;
  const int beg = row_ptr[n];
  const int end = row_ptr[n + 1];

  float4 m4 = make_float4(-1e30f, -1e30f, -1e30f, -1e30f);
  for (int j = beg + lane; j < end; j += 64) {
    float4 a = as4[csr_src[j]];
    m4.x = fmaxf(m4.x, a.x); m4.y = fmaxf(m4.y, a.y);
    m4.z = fmaxf(m4.z, a.z); m4.w = fmaxf(m4.w, a.w);
  }
#pragma unroll
  for (int off = 32; off > 0; off >>= 1) {
    m4.x = fmaxf(m4.x, __shfl_xor(m4.x, off));
    m4.y = fmaxf(m4.y, __shfl_xor(m4.y, off));
    m4.z = fmaxf(m4.z, __shfl_xor(m4.z, off));
    m4.w = fmaxf(m4.w, __shfl_xor(m4.w, off));
  }
  const float ad = comp4(((const float4*)ad_g)[n], head);
  const float mm = lky(ad + comp4(m4, head));

  float lsum = 0.f;
  for (int j0 = beg; j0 < end; j0 += 16) {
    int j = j0 + sub;
    int jc = (j < end) ? j : (end - 1);
    int s = csr_src[jc];
    float w = __expf(lky(as_g[s * NHEAD + head] + ad) - mm);
    w_buf[(size_t)jc * NHEAD + head] = w;   // clamped lanes rewrite same value
    lsum += (j < end) ? w : 0.f;
  }
#pragma unroll
  for (int off = 1; off < 16; off <<= 1) lsum += __shfl_xor(lsum, off);
  if (sub == 0) inv_l[n * NHEAD + head] = 1.f / (lsum + 1e-16f);
}

// ---------------------------------------------------------------------------
// aggregate_sliced: XCD-column-sliced LEAN weighted gather.
// Block b: slice q = b&7 (channels q*32.., 128B, head q>>1), nodes 4*(b>>3)..
// Round-robin dispatch -> slice q pinned to one XCD -> per-XCD h working
// set 6.4 MB (~L2). R10 confirmed bytes: FETCH 435->266 MB. Per-edge work
// here is ONLY {csr, w, h-slice, fma} — no exp, no as-gather (R10 fix).
// ---------------------------------------------------------------------------
__global__ __launch_bounds__(256) void aggregate_sliced(
    const float* __restrict__ h, const float* __restrict__ w_buf,
    const float* __restrict__ inv_l, const int* __restrict__ row_ptr,
    const int* __restrict__ csr_src, const float* __restrict__ bias,
    float* __restrict__ out, int relu_flag, int N) {
  const int q = blockIdx.x & 7;
  const int ng = blockIdx.x >> 3;
  const int wave = threadIdx.x >> 6;
  const int lane = threadIdx.x & 63;
  const int n = ng * 4 + wave;
  if (n >= N) return;
  const int head = q >> 1;
  const int epar = lane >> 5;            // which of 2 concurrent edges
  const int c = lane & 31;               // channel within slice

  const int beg = row_ptr[n];
  const int end = row_ptr[n + 1];
  const float il = inv_l[n * NHEAD + head];
  const float* __restrict__ hsl = h + q * 32 + c;

  float acc = 0.f;
  for (int j0 = beg; j0 < end; j0 += 16) {
    int jc[8];
    float wv[8];
    float hv[8];
#pragma unroll
    for (int u = 0; u < 8; ++u) {
      int j = j0 + 2 * u + epar;
      jc[u] = (j < end) ? j : (end - 1);
    }
    int s[8];
#pragma unroll
    for (int u = 0; u < 8; ++u) s[u] = csr_src[jc[u]];
#pragma unroll
    for (int u = 0; u < 8; ++u) wv[u] = w_buf[(size_t)jc[u] * NHEAD + head];
#pragma unroll
    for (int u = 0; u < 8; ++u) hv[u] = hsl[(size_t)s[u] * HC];
#pragma unroll
    for (int u = 0; u < 8; ++u) {
      float w = (j0 + 2 * u + epar < end) ? wv[u] : 0.f;
      acc = fmaf(w, hv[u], acc);
    }
  }
  acc += __shfl_xor(acc, 32);            // combine the 2 edge-parity halves
  if (epar == 0) {
    float o = acc * il + bias[q * 32 + c];
    if (relu_flag) o = fmaxf(o, 0.f);
    out[(size_t)n * HC + q * 32 + c] = o;
  }
}

// ---------------------------------------------------------------------------
// edge_index dtype sniffer: flag=1 if int64 layout, 0 if int32.
// ---------------------------------------------------------------------------
__global__ void detect_kernel(const int* __restrict__ ei32, int* flag) {
  const int t = threadIdx.x;   // 64 threads
  int bad = 0;
#pragma unroll
  for (int r = 0; r < 4; ++r) {
    int i = r * 64 + t;
    if (ei32[2 * i + 1] != 0) bad = 1;
  }
#pragma unroll
  for (int off = 32; off > 0; off >>= 1) bad |= __shfl_down(bad, off);
  if (t == 0) *flag = bad ? 0 : 1;
}

__device__ inline void edge_pair(const int* __restrict__ ei32,
                                 const long long* __restrict__ ei64, int is64,
                                 int e, int E, int& src, int& dst) {
  if (e < E) {
    if (is64) { src = (int)ei64[e]; dst = (int)ei64[(size_t)E + e]; }
    else      { src = ei32[e];      dst = ei32[(size_t)E + e]; }
  } else {
    src = dst = e - E;   // self loops appended
  }
}

__global__ void count_kernel(const int* __restrict__ ei32, const int* __restrict__ flag,
                             int* __restrict__ cnt, int E, int Nn) {
  int e = blockIdx.x * blockDim.x + threadIdx.x;
  if (e >= E + Nn) return;
  int is64 = *flag;
  int src, dst;
  edge_pair(ei32, (const long long*)ei32, is64, e, E, src, dst);
  atomicAdd(&cnt[dst], 1);
}

__global__ void scatter_kernel(const int* __restrict__ ei32, const int* __restrict__ flag,
                               int* __restrict__ cursor, int* __restrict__ csr_src,
                               int E, int Nn) {
  int e = blockIdx.x * blockDim.x + threadIdx.x;
  if (e >= E + Nn) return;
  int is64 = *flag;
  int src, dst;
  edge_pair(ei32, (const long long*)ei32, is64, e, E, src, dst);
  int pos = atomicAdd(&cursor[dst], 1);
  csr_src[pos] = src;
}

// ---------------------------------------------------------------------------
// hierarchical exclusive scan
// ---------------------------------------------------------------------------
__global__ __launch_bounds__(256) void scan_blocks(
    const int* __restrict__ cnt, int* __restrict__ local,
    int* __restrict__ partials, int Nn) {
  __shared__ int swave[4];
  const int t = threadIdx.x, lane = t & 63, w = t >> 6;
  const int idx = blockIdx.x * 256 + t;
  int v = (idx < Nn) ? cnt[idx] : 0;
  int x = v;
#pragma unroll
  for (int off = 1; off < 64; off <<= 1) {
    int y = __shfl_up(x, off);
    if (lane >= off) x += y;
  }
  if (lane == 63) swave[w] = x;
  __syncthreads();
  int wofs = 0;
#pragma unroll
  for (int i = 0; i < 3; ++i) wofs += (i < w) ? swave[i] : 0;
  if (idx < Nn) local[idx] = wofs + x - v;
  if (t == 255) partials[blockIdx.x] = wofs + x;
}

__global__ __launch_bounds__(256) void scan_partials(
    int* __restrict__ partials, int nb, int* __restrict__ total_out) {
  __shared__ int swave[4];
  const int t = threadIdx.x, lane = t & 63, w = t >> 6;
  int v = (t < nb) ? partials[t] : 0;
  int x = v;
#pragma unroll
  for (int off = 1; off < 64; off <<= 1) {
    int y = __shfl_up(x, off);
    if (lane >= off) x += y;
  }
  if (lane == 63) swave[w] = x;
  __syncthreads();
  int wofs = 0;
#pragma unroll
  for (int i = 0; i < 3; ++i) wofs += (i < w) ? swave[i] : 0;
  int excl = wofs + x - v;
  if (t < nb) partials[t] = excl;
  if (t == nb - 1) *total_out = excl + v;
}

__global__ void add_offsets(const int* __restrict__ local,
                            const int* __restrict__ partials,
                            int* __restrict__ row_ptr, int* __restrict__ cursor,
                            int Nn) {
  const int idx = blockIdx.x * 256 + threadIdx.x;
  if (idx < Nn) {
    int v = local[idx] + partials[blockIdx.x];
    row_ptr[idx] = v;
    cursor[idx] = v;
  }
}

// ---------------------------------------------------------------------------
static inline size_t align_up(size_t v) { return (v + 255) & ~(size_t)255; }

extern "C" void kernel_launch(void* const* d_in, const int* in_sizes, int n_in,
                              void* d_out, int out_size, void* d_ws, size_t ws_size,
                              hipStream_t stream) {
  const float* x      = (const float*)d_in[0];
  const int*   ei32   = (const int*)d_in[1];
  const float* W1     = (const float*)d_in[2];
  const float* asrc1  = (const float*)d_in[3];
  const float* adst1  = (const float*)d_in[4];
  const float* b1     = (const float*)d_in[5];
  const float* W2     = (const float*)d_in[6];
  const float* asrc2  = (const float*)d_in[7];
  const float* adst2  = (const float*)d_in[8];
  const float* b2     = (const float*)d_in[9];
  const float* W3     = (const float*)d_in[10];
  const float* asrc3  = (const float*)d_in[11];
  const float* adst3  = (const float*)d_in[12];
  const float* b3     = (const float*)d_in[13];

  const int N = in_sizes[0] / 128;   // 50000
  const int E = in_sizes[1] / 2;     // 800000
  const int ET = E + N;              // with self loops
  float* out = (float*)d_out;
  const int nb = (N + 255) / 256;

  // ---- workspace carve
  char* w = (char*)d_ws;
  float* H       = (float*)w; w += align_up((size_t)N * HC * sizeof(float));
  float* AS      = (float*)w; w += align_up((size_t)N * NHEAD * sizeof(float));
  float* AD      = (float*)w; w += align_up((size_t)N * NHEAD * sizeof(float));
  float* INVL    = (float*)w; w += align_up((size_t)N * NHEAD * sizeof(float));
  float* WBUF    = (float*)w; w += align_up((size_t)ET * NHEAD * sizeof(float));
  int*   cnt     = (int*)w;   w += align_up((size_t)N * sizeof(int));
  int*   local   = (int*)w;   w += align_up((size_t)N * sizeof(int));
  int*   row_ptr = (int*)w;   w += align_up((size_t)(N + 1) * sizeof(int));
  int*   cursor  = (int*)w;   w += align_up((size_t)(N + 1) * sizeof(int));
  int*   parts   = (int*)w;   w += align_up(256 * sizeof(int));
  int*   csr_src = (int*)w;   w += align_up((size_t)ET * sizeof(int));
  u16*   Wth1    = (u16*)w;   w += align_up((size_t)128 * 256 * sizeof(u16));
  u16*   Wtl1    = (u16*)w;   w += align_up((size_t)128 * 256 * sizeof(u16));
  u16*   Wth2    = (u16*)w;   w += align_up((size_t)256 * 256 * sizeof(u16));
  u16*   Wtl2    = (u16*)w;   w += align_up((size_t)256 * 256 * sizeof(u16));
  u16*   Wth3    = (u16*)w;   w += align_up((size_t)256 * 256 * sizeof(u16));
  u16*   Wtl3    = (u16*)w;   w += align_up((size_t)256 * 256 * sizeof(u16));
  int*   flag    = (int*)w;   w += align_up(sizeof(int));

  // ---- weight conversion + CSR build
  convert_w3<<<(128 * 256 + 2 * 256 * 256 + 255) / 256, 256, 0, stream>>>(
      W1, W2, W3, Wth1, Wtl1, Wth2, Wtl2, Wth3, Wtl3);
  hipMemsetAsync(cnt, 0, (size_t)N * sizeof(int), stream);
  detect_kernel<<<1, 64, 0, stream>>>(ei32, flag);
  count_kernel<<<(ET + 255) / 256, 256, 0, stream>>>(ei32, flag, cnt, E, N);
  scan_blocks<<<nb, 256, 0, stream>>>(cnt, local, parts, N);
  scan_partials<<<1, 256, 0, stream>>>(parts, nb, row_ptr + N);
  add_offsets<<<nb, 256, 0, stream>>>(local, parts, row_ptr, cursor, N);
  scatter_kernel<<<(ET + 255) / 256, 256, 0, stream>>>(ei32, flag, cursor, csr_src, E, N);

  const int nMb = (N + GBM - 1) / GBM;           // 391
  const int gemm_blocks = nMb * 2;               // 1D swizzled grid
  const int ablk = (N + 3) / 4;
  const int sblk = ablk * 8;                     // sliced aggregate grid

  // ---- layer 1 (K=128), ReLU
  gemm_mfma<<<gemm_blocks, 256, 0, stream>>>(x, Wth1, Wtl1, H,
      asrc1, adst1, AS, AD, N, 128, nMb);
  edge_weights<<<ablk, 256, 0, stream>>>(AS, AD, row_ptr, csr_src, WBUF, INVL, N);
  aggregate_sliced<<<sblk, 256, 0, stream>>>(H, WBUF, INVL, row_ptr,
      csr_src, b1, out, 1, N);

  // ---- layer 2 (K=256), ReLU
  gemm_mfma<<<gemm_blocks, 256, 0, stream>>>(out, Wth2, Wtl2, H,
      asrc2, adst2, AS, AD, N, 256, nMb);
  edge_weights<<<ablk, 256, 0, stream>>>(AS, AD, row_ptr, csr_src, WBUF, INVL, N);
  aggregate_sliced<<<sblk, 256, 0, stream>>>(H, WBUF, INVL, row_ptr,
      csr_src, b2, out, 1, N);

  // ---- layer 3 (K=256), no ReLU
  gemm_mfma<<<gemm_blocks, 256, 0, stream>>>(out, Wth3, Wtl3, H,
      asrc3, adst3, AS, AD, N, 256, nMb);
  edge_weights<<<ablk, 256, 0, stream>>>(AS, AD, row_ptr, csr_src, WBUF, INVL, N);
  aggregate_sliced<<<sblk, 256, 0, stream>>>(H, WBUF, INVL, row_ptr,
      csr_src, b3, out, 0, N);
}

// Round 12
// 587.582 us; speedup vs baseline: 1.4027x; 1.2926x over previous
//
#include <hip/hip_runtime.h>
#include <hip/hip_bf16.h>

typedef unsigned short u16;
typedef __attribute__((ext_vector_type(8))) short short8;
typedef __attribute__((ext_vector_type(4))) float f32x4;

#define HC 256      // H*C (all three layers output 256)
#define NHEAD 4

// ---------------------------------------------------------------------------
// bf16 helpers: truncation split (hi = top 16 bits, lo = rne(v - hi))
// ---------------------------------------------------------------------------
__device__ __forceinline__ u16 f2b_rne(float v) {
  __hip_bfloat16 b = __float2bfloat16(v);
  union { __hip_bfloat16 b; u16 u; } cv; cv.b = b; return cv.u;
}

// ---------------------------------------------------------------------------
// W convert (all 3 layers, one dispatch):
// Wth/Wtl[n*K + k] = split_bf16(W[k*256 + n])  (transposed, k-major)
// ---------------------------------------------------------------------------
__device__ __forceinline__ void w_split_store(const float* W, u16* Th, u16* Tl,
                                              int K, int off) {
  int k = off >> 8, n = off & 255;
  float v = W[off];
  unsigned bits = __float_as_uint(v);
  u16 hi = (u16)(bits >> 16);
  float hf = __uint_as_float((unsigned)hi << 16);
  u16 lo = f2b_rne(v - hf);
  Th[n * K + k] = hi;
  Tl[n * K + k] = lo;
}

__global__ void convert_w3(const float* __restrict__ W1, const float* __restrict__ W2,
                           const float* __restrict__ W3,
                           u16* __restrict__ Th1, u16* __restrict__ Tl1,
                           u16* __restrict__ Th2, u16* __restrict__ Tl2,
                           u16* __restrict__ Th3, u16* __restrict__ Tl3) {
  int id = blockIdx.x * 256 + threadIdx.x;
  const int S1 = 128 * 256, S2 = 256 * 256;
  if (id < S1) w_split_store(W1, Th1, Tl1, 128, id);
  else if (id < S1 + S2) w_split_store(W2, Th2, Tl2, 256, id - S1);
  else if (id < S1 + 2 * S2) w_split_store(W3, Th3, Tl3, 256, id - S1 - S2);
}

__device__ __forceinline__ float lky(float e) {
  return (e >= 0.f) ? e : 0.2f * e;
}

__device__ __forceinline__ float comp4(float4 v, int i) {
  return (i == 0) ? v.x : (i == 1) ? v.y : (i == 2) ? v.z : v.w;
}

// ---------------------------------------------------------------------------
// GEMM: C[M,256] = A[M,K] @ B[K,256] via split-bf16 MFMA 16x16x32.
// Block 128x128x64, 4 waves 2x2, wave tile 64x64 (4x4 frags).
// Co-XCD pairing swizzle (A-panel L2 sharing). Fused alpha epilogue.
// ---------------------------------------------------------------------------
#define GBM 128
#define GBN 128
#define GBK 64

__global__ __launch_bounds__(256, 2) void gemm_mfma(
    const float* __restrict__ A, const u16* __restrict__ Bth,
    const u16* __restrict__ Btl, float* __restrict__ C,
    const float* __restrict__ a_src, const float* __restrict__ a_dst,
    float* __restrict__ AS, float* __restrict__ AD, int M, int K, int nMb) {
  __shared__ u16 AH[128 * 64], AL[128 * 64], BH[128 * 64], BL[128 * 64];
  const int tid = threadIdx.x;
  const int lane = tid & 63;
  const int wave = tid >> 6;
  const int wm = (wave & 1) * 64;
  const int wn = (wave >> 1) * 64;

  const int bid = blockIdx.x;
  const int g = bid >> 4;
  const int r = bid & 15;
  const int base = g * 8;
  const int rem = nMb - base;
  int bmi, bni;
  if (rem >= 8) { bmi = base + (r & 7); bni = r >> 3; }
  else          { bmi = base + (r % rem); bni = r / rem; }
  const int bm = bmi * GBM;
  const int bn = bni * GBN;

  const int srow = tid >> 1;
  const int skh  = (tid & 1) * 32;

  f32x4 acc[4][4] = {};
  const int agm = (bm + srow < M) ? (bm + srow) : (M - 1);

  for (int bk = 0; bk < K; bk += GBK) {
    float4 a0[4], a1[4];
    const float* arow = A + (size_t)agm * K + bk + skh;
#pragma unroll
    for (int u = 0; u < 4; ++u) {
      a0[u] = ((const float4*)arow)[2 * u];
      a1[u] = ((const float4*)arow)[2 * u + 1];
    }
    short8 sbh[4], sbl[4];
    const u16* bhrow = Bth + (size_t)(bn + srow) * K + bk + skh;
    const u16* blrow = Btl + (size_t)(bn + srow) * K + bk + skh;
#pragma unroll
    for (int u = 0; u < 4; ++u) {
      sbh[u] = *(const short8*)(bhrow + 8 * u);
      sbl[u] = *(const short8*)(blrow + 8 * u);
    }
    __syncthreads();
#pragma unroll
    for (int u = 0; u < 4; ++u) {
      int idx = (srow * 64 + skh + u * 8) ^ ((srow & 7) << 3);
      float va[8] = {a0[u].x, a0[u].y, a0[u].z, a0[u].w,
                     a1[u].x, a1[u].y, a1[u].z, a1[u].w};
      short8 hi, lo;
#pragma unroll
      for (int j = 0; j < 8; ++j) {
        unsigned bits = __float_as_uint(va[j]);
        u16 h = (u16)(bits >> 16);
        float hf = __uint_as_float((unsigned)h << 16);
        u16 l = f2b_rne(va[j] - hf);
        ((short*)&hi)[j] = (short)h;
        ((short*)&lo)[j] = (short)l;
      }
      *(short8*)&AH[idx] = hi;
      *(short8*)&AL[idx] = lo;
      *(short8*)&BH[idx] = sbh[u];
      *(short8*)&BL[idx] = sbl[u];
    }
    __syncthreads();
#pragma unroll
    for (int ks = 0; ks < 2; ++ks) {
      const int k0 = ks * 32 + (lane >> 4) * 8;
      short8 fah[4], fal[4], fbh[4], fbl[4];
#pragma unroll
      for (int mt = 0; mt < 4; ++mt) {
        int rr = wm + mt * 16 + (lane & 15);
        int idx = (rr * 64 + k0) ^ ((rr & 7) << 3);
        fah[mt] = *(const short8*)&AH[idx];
        fal[mt] = *(const short8*)&AL[idx];
      }
#pragma unroll
      for (int nt = 0; nt < 4; ++nt) {
        int rr = wn + nt * 16 + (lane & 15);
        int idx = (rr * 64 + k0) ^ ((rr & 7) << 3);
        fbh[nt] = *(const short8*)&BH[idx];
        fbl[nt] = *(const short8*)&BL[idx];
      }
#pragma unroll
      for (int mt = 0; mt < 4; ++mt)
#pragma unroll
        for (int nt = 0; nt < 4; ++nt) {
          acc[mt][nt] = __builtin_amdgcn_mfma_f32_16x16x32_bf16(
              fbh[nt], fah[mt], acc[mt][nt], 0, 0, 0);
          acc[mt][nt] = __builtin_amdgcn_mfma_f32_16x16x32_bf16(
              fbh[nt], fal[mt], acc[mt][nt], 0, 0, 0);
          acc[mt][nt] = __builtin_amdgcn_mfma_f32_16x16x32_bf16(
              fbl[nt], fah[mt], acc[mt][nt], 0, 0, 0);
        }
    }
  }
  // ---- fused alpha epilogue + C store
  const int headq = (bn + wn) >> 6;
  float4 sa[4], da[4];
#pragma unroll
  for (int nt = 0; nt < 4; ++nt) {
    sa[nt] = ((const float4*)a_src)[headq * 16 + nt * 4 + (lane >> 4)];
    da[nt] = ((const float4*)a_dst)[headq * 16 + nt * 4 + (lane >> 4)];
  }
#pragma unroll
  for (int mt = 0; mt < 4; ++mt) {
    const int row = bm + wm + mt * 16 + (lane & 15);
    float ps = 0.f, pd = 0.f;
#pragma unroll
    for (int nt = 0; nt < 4; ++nt) {
      ps += acc[mt][nt][0] * sa[nt].x + acc[mt][nt][1] * sa[nt].y +
            acc[mt][nt][2] * sa[nt].z + acc[mt][nt][3] * sa[nt].w;
      pd += acc[mt][nt][0] * da[nt].x + acc[mt][nt][1] * da[nt].y +
            acc[mt][nt][2] * da[nt].z + acc[mt][nt][3] * da[nt].w;
    }
    ps += __shfl_xor(ps, 16); ps += __shfl_xor(ps, 32);
    pd += __shfl_xor(pd, 16); pd += __shfl_xor(pd, 32);
    if (row < M) {
      float* cp = C + (size_t)row * HC + bn + wn + (lane >> 4) * 4;
#pragma unroll
      for (int nt = 0; nt < 4; ++nt)
        *(f32x4*)(cp + nt * 16) = acc[mt][nt];
      if ((lane >> 4) == 0) {
        AS[row * NHEAD + headq] = ps;
        AD[row * NHEAD + headq] = pd;
      }
    }
  }
}

// ---------------------------------------------------------------------------
// aggregate: fused 1-wave-per-node gather (best of 6 measured variants:
// 127.6us vs 132/148/169/187/203 for 2-wave/lean/sliced forms).
// Serves 870MB logical at ~6.8TB/s combined L2+L3; miss side pinned at
// ~3.9TB/s across all variants. Lane owns float4, head=lane>>4.
// ---------------------------------------------------------------------------
__global__ __launch_bounds__(256) void aggregate_kernel(
    const float* __restrict__ h, const float* __restrict__ as_g,
    const float* __restrict__ ad_g, const int* __restrict__ row_ptr,
    const int* __restrict__ csr_src, const float* __restrict__ bias,
    float* __restrict__ out, int relu_flag, int N) {
  const int wave = threadIdx.x >> 6;
  const int lane = threadIdx.x & 63;
  const int n = blockIdx.x * 4 + wave;
  if (n >= N) return;
  const int head = lane >> 4;
  const float4* __restrict__ h4 = (const float4*)h;
  const float4* __restrict__ as4 = (const float4*)as_g;

  const int beg = row_ptr[n];
  const int end = row_ptr[n + 1];

  // ---- phase 1: per-head max of as over in-edges (leaky monotone => exact)
  float4 m4 = make_float4(-1e30f, -1e30f, -1e30f, -1e30f);
  for (int j = beg + lane; j < end; j += 64) {
    float4 a = as4[csr_src[j]];
    m4.x = fmaxf(m4.x, a.x); m4.y = fmaxf(m4.y, a.y);
    m4.z = fmaxf(m4.z, a.z); m4.w = fmaxf(m4.w, a.w);
  }
#pragma unroll
  for (int off = 32; off > 0; off >>= 1) {
    m4.x = fmaxf(m4.x, __shfl_xor(m4.x, off));
    m4.y = fmaxf(m4.y, __shfl_xor(m4.y, off));
    m4.z = fmaxf(m4.z, __shfl_xor(m4.z, off));
    m4.w = fmaxf(m4.w, __shfl_xor(m4.w, off));
  }
  const float ad = comp4(((const float4*)ad_g)[n], head);
  float mm = lky(ad + comp4(m4, head));

  // ---- phase 2: single pass, 8-deep chunked prefetch
  float l = 0.f;
  float4 acc = make_float4(0.f, 0.f, 0.f, 0.f);
  for (int j0 = beg; j0 < end; j0 += 8) {
    int s[8];
    float ae[8];
    float4 hv[8];
#pragma unroll
    for (int u = 0; u < 8; ++u) {
      int j = j0 + u;
      s[u] = csr_src[(j < end) ? j : (end - 1)];
    }
#pragma unroll
    for (int u = 0; u < 8; ++u) ae[u] = as_g[s[u] * NHEAD + head];
#pragma unroll
    for (int u = 0; u < 8; ++u) hv[u] = h4[(size_t)s[u] * 64 + lane];
#pragma unroll
    for (int u = 0; u < 8; ++u) {
      float p = __expf(lky(ae[u] + ad) - mm);
      p = (j0 + u < end) ? p : 0.f;
      l += p;
      acc.x = fmaf(p, hv[u].x, acc.x);
      acc.y = fmaf(p, hv[u].y, acc.y);
      acc.z = fmaf(p, hv[u].z, acc.z);
      acc.w = fmaf(p, hv[u].w, acc.w);
    }
  }
  const float inv = 1.f / (l + 1e-16f);
  float4 b4 = ((const float4*)bias)[lane];
  float4 o;
  o.x = acc.x * inv + b4.x; o.y = acc.y * inv + b4.y;
  o.z = acc.z * inv + b4.z; o.w = acc.w * inv + b4.w;
  if (relu_flag) {
    o.x = fmaxf(o.x, 0.f); o.y = fmaxf(o.y, 0.f);
    o.z = fmaxf(o.z, 0.f); o.w = fmaxf(o.w, 0.f);
  }
  ((float4*)out)[(size_t)n * 64 + lane] = o;
}

// ---------------------------------------------------------------------------
// edge_index dtype sniffer: flag=1 if int64 layout, 0 if int32.
// ---------------------------------------------------------------------------
__global__ void detect_kernel(const int* __restrict__ ei32, int* flag) {
  const int t = threadIdx.x;   // 64 threads
  int bad = 0;
#pragma unroll
  for (int r = 0; r < 4; ++r) {
    int i = r * 64 + t;
    if (ei32[2 * i + 1] != 0) bad = 1;
  }
#pragma unroll
  for (int off = 32; off > 0; off >>= 1) bad |= __shfl_down(bad, off);
  if (t == 0) *flag = bad ? 0 : 1;
}

__device__ inline void edge_pair(const int* __restrict__ ei32,
                                 const long long* __restrict__ ei64, int is64,
                                 int e, int E, int& src, int& dst) {
  if (e < E) {
    if (is64) { src = (int)ei64[e]; dst = (int)ei64[(size_t)E + e]; }
    else      { src = ei32[e];      dst = ei32[(size_t)E + e]; }
  } else {
    src = dst = e - E;   // self loops appended
  }
}

__global__ void count_kernel(const int* __restrict__ ei32, const int* __restrict__ flag,
                             int* __restrict__ cnt, int E, int Nn) {
  int e = blockIdx.x * blockDim.x + threadIdx.x;
  if (e >= E + Nn) return;
  int is64 = *flag;
  int src, dst;
  edge_pair(ei32, (const long long*)ei32, is64, e, E, src, dst);
  atomicAdd(&cnt[dst], 1);
}

__global__ void scatter_kernel(const int* __restrict__ ei32, const int* __restrict__ flag,
                               int* __restrict__ cursor, int* __restrict__ csr_src,
                               int E, int Nn) {
  int e = blockIdx.x * blockDim.x + threadIdx.x;
  if (e >= E + Nn) return;
  int is64 = *flag;
  int src, dst;
  edge_pair(ei32, (const long long*)ei32, is64, e, E, src, dst);
  int pos = atomicAdd(&cursor[dst], 1);
  csr_src[pos] = src;
}

// ---------------------------------------------------------------------------
// hierarchical exclusive scan
// ---------------------------------------------------------------------------
__global__ __launch_bounds__(256) void scan_blocks(
    const int* __restrict__ cnt, int* __restrict__ local,
    int* __restrict__ partials, int Nn) {
  __shared__ int swave[4];
  const int t = threadIdx.x, lane = t & 63, w = t >> 6;
  const int idx = blockIdx.x * 256 + t;
  int v = (idx < Nn) ? cnt[idx] : 0;
  int x = v;
#pragma unroll
  for (int off = 1; off < 64; off <<= 1) {
    int y = __shfl_up(x, off);
    if (lane >= off) x += y;
  }
  if (lane == 63) swave[w] = x;
  __syncthreads();
  int wofs = 0;
#pragma unroll
  for (int i = 0; i < 3; ++i) wofs += (i < w) ? swave[i] : 0;
  if (idx < Nn) local[idx] = wofs + x - v;
  if (t == 255) partials[blockIdx.x] = wofs + x;
}

__global__ __launch_bounds__(256) void scan_partials(
    int* __restrict__ partials, int nb, int* __restrict__ total_out) {
  __shared__ int swave[4];
  const int t = threadIdx.x, lane = t & 63, w = t >> 6;
  int v = (t < nb) ? partials[t] : 0;
  int x = v;
#pragma unroll
  for (int off = 1; off < 64; off <<= 1) {
    int y = __shfl_up(x, off);
    if (lane >= off) x += y;
  }
  if (lane == 63) swave[w] = x;
  __syncthreads();
  int wofs = 0;
#pragma unroll
  for (int i = 0; i < 3; ++i) wofs += (i < w) ? swave[i] : 0;
  int excl = wofs + x - v;
  if (t < nb) partials[t] = excl;
  if (t == nb - 1) *total_out = excl + v;
}

__global__ void add_offsets(const int* __restrict__ local,
                            const int* __restrict__ partials,
                            int* __restrict__ row_ptr, int* __restrict__ cursor,
                            int Nn) {
  const int idx = blockIdx.x * 256 + threadIdx.x;
  if (idx < Nn) {
    int v = local[idx] + partials[blockIdx.x];
    row_ptr[idx] = v;
    cursor[idx] = v;
  }
}

// ---------------------------------------------------------------------------
static inline size_t align_up(size_t v) { return (v + 255) & ~(size_t)255; }

extern "C" void kernel_launch(void* const* d_in, const int* in_sizes, int n_in,
                              void* d_out, int out_size, void* d_ws, size_t ws_size,
                              hipStream_t stream) {
  const float* x      = (const float*)d_in[0];
  const int*   ei32   = (const int*)d_in[1];
  const float* W1     = (const float*)d_in[2];
  const float* asrc1  = (const float*)d_in[3];
  const float* adst1  = (const float*)d_in[4];
  const float* b1     = (const float*)d_in[5];
  const float* W2     = (const float*)d_in[6];
  const float* asrc2  = (const float*)d_in[7];
  const float* adst2  = (const float*)d_in[8];
  const float* b2     = (const float*)d_in[9];
  const float* W3     = (const float*)d_in[10];
  const float* asrc3  = (const float*)d_in[11];
  const float* adst3  = (const float*)d_in[12];
  const float* b3     = (const float*)d_in[13];

  const int N = in_sizes[0] / 128;   // 50000
  const int E = in_sizes[1] / 2;     // 800000
  const int ET = E + N;              // with self loops
  float* out = (float*)d_out;
  const int nb = (N + 255) / 256;

  // ---- workspace carve
  char* w = (char*)d_ws;
  float* H       = (float*)w; w += align_up((size_t)N * HC * sizeof(float));
  float* AS      = (float*)w; w += align_up((size_t)N * NHEAD * sizeof(float));
  float* AD      = (float*)w; w += align_up((size_t)N * NHEAD * sizeof(float));
  int*   cnt     = (int*)w;   w += align_up((size_t)N * sizeof(int));
  int*   local   = (int*)w;   w += align_up((size_t)N * sizeof(int));
  int*   row_ptr = (int*)w;   w += align_up((size_t)(N + 1) * sizeof(int));
  int*   cursor  = (int*)w;   w += align_up((size_t)(N + 1) * sizeof(int));
  int*   parts   = (int*)w;   w += align_up(256 * sizeof(int));
  int*   csr_src = (int*)w;   w += align_up((size_t)ET * sizeof(int));
  u16*   Wth1    = (u16*)w;   w += align_up((size_t)128 * 256 * sizeof(u16));
  u16*   Wtl1    = (u16*)w;   w += align_up((size_t)128 * 256 * sizeof(u16));
  u16*   Wth2    = (u16*)w;   w += align_up((size_t)256 * 256 * sizeof(u16));
  u16*   Wtl2    = (u16*)w;   w += align_up((size_t)256 * 256 * sizeof(u16));
  u16*   Wth3    = (u16*)w;   w += align_up((size_t)256 * 256 * sizeof(u16));
  u16*   Wtl3    = (u16*)w;   w += align_up((size_t)256 * 256 * sizeof(u16));
  int*   flag    = (int*)w;   w += align_up(sizeof(int));

  // ---- weight conversion (one dispatch) + CSR build
  convert_w3<<<(128 * 256 + 2 * 256 * 256 + 255) / 256, 256, 0, stream>>>(
      W1, W2, W3, Wth1, Wtl1, Wth2, Wtl2, Wth3, Wtl3);
  hipMemsetAsync(cnt, 0, (size_t)N * sizeof(int), stream);
  detect_kernel<<<1, 64, 0, stream>>>(ei32, flag);
  count_kernel<<<(ET + 255) / 256, 256, 0, stream>>>(ei32, flag, cnt, E, N);
  scan_blocks<<<nb, 256, 0, stream>>>(cnt, local, parts, N);
  scan_partials<<<1, 256, 0, stream>>>(parts, nb, row_ptr + N);
  add_offsets<<<nb, 256, 0, stream>>>(local, parts, row_ptr, cursor, N);
  scatter_kernel<<<(ET + 255) / 256, 256, 0, stream>>>(ei32, flag, cursor, csr_src, E, N);

  const int nMb = (N + GBM - 1) / GBM;           // 391
  const int gemm_blocks = nMb * 2;               // 1D swizzled grid
  const int ablk = (N + 3) / 4;

  // ---- layer 1 (K=128), ReLU
  gemm_mfma<<<gemm_blocks, 256, 0, stream>>>(x, Wth1, Wtl1, H,
      asrc1, adst1, AS, AD, N, 128, nMb);
  aggregate_kernel<<<ablk, 256, 0, stream>>>(H, AS, AD, row_ptr, csr_src, b1, out, 1, N);

  // ---- layer 2 (K=256), ReLU
  gemm_mfma<<<gemm_blocks, 256, 0, stream>>>(out, Wth2, Wtl2, H,
      asrc2, adst2, AS, AD, N, 256, nMb);
  aggregate_kernel<<<ablk, 256, 0, stream>>>(H, AS, AD, row_ptr, csr_src, b2, out, 1, N);

  // ---- layer 3 (K=256), no ReLU
  gemm_mfma<<<gemm_blocks, 256, 0, stream>>>(out, Wth3, Wtl3, H,
      asrc3, adst3, AS, AD, N, 256, nMb);
  aggregate_kernel<<<ablk, 256, 0, stream>>>(H, AS, AD, row_ptr, csr_src, b3, out, 0, N);
}